// Round 1
// baseline (1473.728 us; speedup 1.0000x reference)
//
#include <hip/hip_runtime.h>

#define N_NODES 100000
#define N_EDGES 1600000
#define NGRAPH  64
#define DIN     128
#define HID     256
#define GA      6

// ---------------- CSR build (counting sort by dst) ----------------

__global__ __launch_bounds__(256) void hist_kernel(const int* __restrict__ dst,
                                                   int* __restrict__ deg) {
  int e = blockIdx.x * 256 + threadIdx.x;
  if (e < N_EDGES) atomicAdd(&deg[dst[e]], 1);
}

// single-block scan: reads deg (in cursor buf), writes csr[i]=excl and cursor[i]=excl
__global__ __launch_bounds__(1024) void scan_kernel(int* __restrict__ deg,
                                                    int* __restrict__ csr) {
  __shared__ int tmp[1024];
  int tid = threadIdx.x;
  int carry = 0;
  for (int base = 0; base < N_NODES; base += 1024) {
    int i = base + tid;
    int v = (i < N_NODES) ? deg[i] : 0;
    tmp[tid] = v;
    __syncthreads();
    for (int off = 1; off < 1024; off <<= 1) {
      int t = (tid >= off) ? tmp[tid - off] : 0;
      __syncthreads();
      tmp[tid] += t;
      __syncthreads();
    }
    int excl = carry + tmp[tid] - v;
    if (i < N_NODES) { csr[i] = excl; deg[i] = excl; }
    carry += tmp[1023];
    __syncthreads();
  }
  if (tid == 0) csr[N_NODES] = carry;
}

__global__ __launch_bounds__(256) void scatter_kernel(const int* __restrict__ src,
                                                      const int* __restrict__ dst,
                                                      int* __restrict__ cursor,
                                                      int* __restrict__ ssrc) {
  int e = blockIdx.x * 256 + threadIdx.x;
  if (e < N_EDGES) {
    int slot = atomicAdd(&cursor[dst[e]], 1);
    ssrc[slot] = src[e];
  }
}

// ---------------- aggregation: out[i] = x[i] + sum_{j in in(i)} x[j] ----------------

// D=128: one wave per node, float2 per lane
__global__ __launch_bounds__(256) void agg1_kernel(const float* __restrict__ x,
                                                   const int* __restrict__ csr,
                                                   const int* __restrict__ ssrc,
                                                   float* __restrict__ out) {
  int node = blockIdx.x * 4 + (threadIdx.x >> 6);
  int lane = threadIdx.x & 63;
  int d = lane * 2;
  float2 acc = *(const float2*)&x[(size_t)node * DIN + d];
  int s = csr[node], e = csr[node + 1];
  for (int i = s; i < e; i++) {
    int sn = ssrc[i];
    float2 v = *(const float2*)&x[(size_t)sn * DIN + d];
    acc.x += v.x; acc.y += v.y;
  }
  *(float2*)&out[(size_t)node * DIN + d] = acc;
}

// D=256: one wave per node, float4 per lane
__global__ __launch_bounds__(256) void agg2_kernel(const float* __restrict__ x,
                                                   const int* __restrict__ csr,
                                                   const int* __restrict__ ssrc,
                                                   float* __restrict__ out) {
  int node = blockIdx.x * 4 + (threadIdx.x >> 6);
  int lane = threadIdx.x & 63;
  int d = lane * 4;
  float4 acc = *(const float4*)&x[(size_t)node * HID + d];
  int s = csr[node], e = csr[node + 1];
  for (int i = s; i < e; i++) {
    int sn = ssrc[i];
    float4 v = *(const float4*)&x[(size_t)sn * HID + d];
    acc.x += v.x; acc.y += v.y; acc.z += v.z; acc.w += v.w;
  }
  *(float4*)&out[(size_t)node * HID + d] = acc;
}

// ---------------- f32 GEMM: C[N][256] = act(A[N][K] @ W[K][256] + b) ----------------
// 64 rows per block, full 256-col width (allows later per-row in-place use).
template<int K, bool RELU>
__global__ __launch_bounds__(256) void gemm_kernel(const float* __restrict__ A,
                                                   const float* __restrict__ W,
                                                   const float* __restrict__ bias,
                                                   float* __restrict__ C) {
  constexpr int BK = 32;
  __shared__ float AsT[BK][68];    // A tile transposed, padded
  __shared__ float Ws[BK][260];    // W tile, padded
  const int tid = threadIdx.x;
  const int tx = tid & 15;         // col group: cols tx*4 + 64*j
  const int ty = tid >> 4;         // row group: rows ty*4 .. +3
  const int rowBase = blockIdx.x * 64;

  float acc[4][16];
#pragma unroll
  for (int r = 0; r < 4; r++)
#pragma unroll
    for (int c = 0; c < 16; c++) acc[r][c] = 0.f;

  for (int k0 = 0; k0 < K; k0 += BK) {
    // stage A tile (64 x 32), transposed
#pragma unroll
    for (int i = 0; i < 2; i++) {
      int idx = tid + i * 256;          // 0..511
      int r   = idx >> 3;               // 0..63
      int kc  = (idx & 7) << 2;         // 0..28
      int gr  = rowBase + r; if (gr >= N_NODES) gr = N_NODES - 1;
      float4 v = *(const float4*)&A[(size_t)gr * K + k0 + kc];
      AsT[kc + 0][r] = v.x; AsT[kc + 1][r] = v.y;
      AsT[kc + 2][r] = v.z; AsT[kc + 3][r] = v.w;
    }
    // stage W tile (32 x 256)
#pragma unroll
    for (int i = 0; i < 8; i++) {
      int idx = tid + i * 256;          // 0..2047
      int wr  = idx >> 6;               // 0..31
      int wc  = (idx & 63) << 2;        // 0..252
      *(float4*)&Ws[wr][wc] = *(const float4*)&W[(size_t)(k0 + wr) * HID + wc];
    }
    __syncthreads();
#pragma unroll
    for (int k = 0; k < BK; k++) {
      float4 a  = *(const float4*)&AsT[k][ty << 2];
      float4 b0 = *(const float4*)&Ws[k][tx * 4];
      float4 b1 = *(const float4*)&Ws[k][tx * 4 + 64];
      float4 b2 = *(const float4*)&Ws[k][tx * 4 + 128];
      float4 b3 = *(const float4*)&Ws[k][tx * 4 + 192];
      float av[4] = {a.x, a.y, a.z, a.w};
      float bv[16] = {b0.x, b0.y, b0.z, b0.w, b1.x, b1.y, b1.z, b1.w,
                      b2.x, b2.y, b2.z, b2.w, b3.x, b3.y, b3.z, b3.w};
#pragma unroll
      for (int r = 0; r < 4; r++)
#pragma unroll
        for (int c = 0; c < 16; c++)
          acc[r][c] = fmaf(av[r], bv[c], acc[r][c]);
    }
    __syncthreads();
  }
  // epilogue
#pragma unroll
  for (int j = 0; j < 4; j++) {
    int col = tx * 4 + j * 64;
    float4 bb = *(const float4*)&bias[col];
#pragma unroll
    for (int r = 0; r < 4; r++) {
      int gr = rowBase + (ty << 2) + r;
      if (gr < N_NODES) {
        float4 o;
        o.x = acc[r][j * 4 + 0] + bb.x;
        o.y = acc[r][j * 4 + 1] + bb.y;
        o.z = acc[r][j * 4 + 2] + bb.z;
        o.w = acc[r][j * 4 + 3] + bb.w;
        if (RELU) {
          o.x = fmaxf(o.x, 0.f); o.y = fmaxf(o.y, 0.f);
          o.z = fmaxf(o.z, 0.f); o.w = fmaxf(o.w, 0.f);
        }
        *(float4*)&C[(size_t)gr * HID + col] = o;
      }
    }
  }
}

// ---------------- pooling (batch sorted -> running per-graph sums) ----------------

__global__ __launch_bounds__(256) void pool_kernel(const float* __restrict__ H,
                                                   const int* __restrict__ batch,
                                                   float* __restrict__ sums,
                                                   float* __restrict__ cnts) {
  int d = threadIdx.x;                  // dim 0..255
  int n0 = blockIdx.x * 128;
  int n1 = n0 + 128; if (n1 > N_NODES) n1 = N_NODES;
  if (n0 >= N_NODES) return;
  int cur = batch[n0];
  float run = 0.f, runc = 0.f;
  for (int i = n0; i < n1; i++) {
    int b = batch[i];
    if (b != cur) {
      atomicAdd(&sums[(size_t)cur * HID + d], run);
      if (d == 0) atomicAdd(&cnts[cur], runc);
      run = 0.f; runc = 0.f; cur = b;
    }
    run += H[(size_t)i * HID + d];
    runc += 1.f;
  }
  atomicAdd(&sums[(size_t)cur * HID + d], run);
  if (d == 0) atomicAdd(&cnts[cur], runc);
}

// ---------------- head: relu(g@wf1+bf1) @ wf2 + bf2 ----------------

__global__ __launch_bounds__(256) void head_kernel(const float* __restrict__ sums,
                                                   const float* __restrict__ cnts,
                                                   const float* __restrict__ gattr,
                                                   const float* __restrict__ wf1,
                                                   const float* __restrict__ bf1,
                                                   const float* __restrict__ wf2,
                                                   const float* __restrict__ bf2,
                                                   float* __restrict__ out) {
  int g = blockIdx.x, tid = threadIdx.x;
  __shared__ float gv[HID + GA];
  __shared__ float red[256];
  float c = cnts[g]; c = fmaxf(c, 1.0f);
  gv[tid] = sums[(size_t)g * HID + tid] / c;
  if (tid < GA) gv[HID + tid] = gattr[g * GA + tid];
  __syncthreads();
  float acc = bf1[tid];
  for (int k = 0; k < HID + GA; k++)
    acc = fmaf(gv[k], wf1[(size_t)k * HID + tid], acc);
  float h = fmaxf(acc, 0.f);
  red[tid] = h * wf2[tid];
  __syncthreads();
  for (int s = 128; s > 0; s >>= 1) {
    if (tid < s) red[tid] += red[tid + s];
    __syncthreads();
  }
  if (tid == 0) out[g] = red[0] + bf2[0];
}

// ---------------- launch ----------------

extern "C" void kernel_launch(void* const* d_in, const int* in_sizes, int n_in,
                              void* d_out, int out_size, void* d_ws, size_t ws_size,
                              hipStream_t stream) {
  const float* x     = (const float*)d_in[0];
  const int*   eidx  = (const int*)d_in[1];
  const int*   batch = (const int*)d_in[2];
  const float* gattr = (const float*)d_in[3];
  const float* w1a = (const float*)d_in[4];  const float* b1a = (const float*)d_in[5];
  const float* w1b = (const float*)d_in[6];  const float* b1b = (const float*)d_in[7];
  const float* w2a = (const float*)d_in[8];  const float* b2a = (const float*)d_in[9];
  const float* w2b = (const float*)d_in[10]; const float* b2b = (const float*)d_in[11];
  const float* wf1 = (const float*)d_in[12]; const float* bf1 = (const float*)d_in[13];
  const float* wf2 = (const float*)d_in[14]; const float* bf2 = (const float*)d_in[15];
  float* out = (float*)d_out;

  const int* esrc = eidx;
  const int* edst = eidx + N_EDGES;

  char* w = (char*)d_ws;
  float* X      = (float*)w; w += (size_t)N_NODES * HID * 4;   // 102.4 MB
  float* Y      = (float*)w; w += (size_t)N_NODES * HID * 4;   // 102.4 MB
  int*   csr    = (int*)w;   w += (size_t)(N_NODES + 4) * 4;
  int*   cursor = (int*)w;   w += (size_t)N_NODES * 4;
  int*   ssrc   = (int*)w;   w += (size_t)N_EDGES * 4;
  float* sums   = (float*)w; w += (size_t)NGRAPH * HID * 4;
  float* cnts   = (float*)w; w += (size_t)NGRAPH * 4;

  hipMemsetAsync(cursor, 0, (size_t)N_NODES * 4, stream);
  hipMemsetAsync(sums, 0, (size_t)(NGRAPH * HID + NGRAPH) * 4, stream);

  hist_kernel<<<N_EDGES / 256, 256, 0, stream>>>(edst, cursor);
  scan_kernel<<<1, 1024, 0, stream>>>(cursor, csr);
  scatter_kernel<<<N_EDGES / 256, 256, 0, stream>>>(esrc, edst, cursor, ssrc);

  // conv1
  agg1_kernel<<<N_NODES / 4, 256, 0, stream>>>(x, csr, ssrc, X);
  gemm_kernel<DIN, true><<<(N_NODES + 63) / 64, 256, 0, stream>>>(X, w1a, b1a, Y);
  gemm_kernel<HID, true><<<(N_NODES + 63) / 64, 256, 0, stream>>>(Y, w1b, b1b, X);
  // conv2
  agg2_kernel<<<N_NODES / 4, 256, 0, stream>>>(X, csr, ssrc, Y);
  gemm_kernel<HID, true><<<(N_NODES + 63) / 64, 256, 0, stream>>>(Y, w2a, b2a, X);
  gemm_kernel<HID, false><<<(N_NODES + 63) / 64, 256, 0, stream>>>(X, w2b, b2b, Y);
  // pool + head
  pool_kernel<<<(N_NODES + 127) / 128, 256, 0, stream>>>(Y, batch, sums, cnts);
  head_kernel<<<NGRAPH, 256, 0, stream>>>(sums, cnts, gattr, wf1, bf1, wf2, bf2, out);
}

// Round 2
// 672.003 us; speedup vs baseline: 2.1930x; 2.1930x over previous
//
#include <hip/hip_runtime.h>

#define N_NODES 100000
#define N_EDGES 1600000
#define NGRAPH  64
#define DIN     128
#define HID     256
#define GA      6

typedef __attribute__((ext_vector_type(8))) short bf16x8;
typedef __attribute__((ext_vector_type(4))) float f32x4;

__device__ __forceinline__ unsigned short f2bf(float f) {
  unsigned int u = __float_as_uint(f);
  u += 0x7fffu + ((u >> 16) & 1u);
  return (unsigned short)(u >> 16);
}
__device__ __forceinline__ float bf_lo(unsigned int u) { return __uint_as_float(u << 16); }
__device__ __forceinline__ float bf_hi(unsigned int u) { return __uint_as_float(u & 0xffff0000u); }
__device__ __forceinline__ unsigned int packbf(float lo, float hi) {
  return (unsigned int)f2bf(lo) | ((unsigned int)f2bf(hi) << 16);
}

__device__ __forceinline__ void gload16(const void* g, void* l) {
  __builtin_amdgcn_global_load_lds(
      (const __attribute__((address_space(1))) unsigned int*)g,
      (__attribute__((address_space(3))) unsigned int*)l, 16, 0, 0);
}

// ---------------- prep: f32 -> bf16 conversions ----------------

__global__ __launch_bounds__(256) void cvt_x_kernel(const float* __restrict__ in,
                                                    unsigned short* __restrict__ out) {
  size_t idx = ((size_t)blockIdx.x * 256 + threadIdx.x) * 4;  // 12.8M total, exact
  float4 v = *(const float4*)&in[idx];
  ushort4 o;
  o.x = f2bf(v.x); o.y = f2bf(v.y); o.z = f2bf(v.z); o.w = f2bf(v.w);
  *(ushort4*)&out[idx] = o;
}

// out[n*K+k] = bf16(in[k*256+n])  (transpose + convert); K = 1<<shift
__global__ __launch_bounds__(256) void cvt_w_kernel(const float* __restrict__ in,
                                                    unsigned short* __restrict__ out,
                                                    int shift) {
  int idx = blockIdx.x * 256 + threadIdx.x;
  int K = 1 << shift;
  int n = idx >> shift;
  int k = idx & (K - 1);
  out[idx] = f2bf(in[(size_t)k * HID + n]);
}

// ---------------- CSR build (counting sort by dst) ----------------

__global__ __launch_bounds__(256) void hist_kernel(const int* __restrict__ dst,
                                                   int* __restrict__ deg) {
  int e = blockIdx.x * 256 + threadIdx.x;
  atomicAdd(&deg[dst[e]], 1);
}

// single block: deg (counts) -> exclusive prefix written to csr AND deg (cursor init)
__global__ __launch_bounds__(1024) void scan_kernel(int* __restrict__ deg,
                                                    int* __restrict__ csr) {
  __shared__ int wsum[16];
  const int tid = threadIdx.x;
  const int lane = tid & 63, wid = tid >> 6;
  int carry = 0;
  for (int base = 0; base < N_NODES; base += 4096) {
    int i0 = base + tid * 4;
    int4 v = make_int4(0, 0, 0, 0);
    if (i0 + 3 < N_NODES) {
      v = *(const int4*)&deg[i0];
    } else if (i0 < N_NODES) {
      v.x = deg[i0];
      if (i0 + 1 < N_NODES) v.y = deg[i0 + 1];
      if (i0 + 2 < N_NODES) v.z = deg[i0 + 2];
    }
    int s = v.x + v.y + v.z + v.w;
    int sc = s;
#pragma unroll
    for (int off = 1; off < 64; off <<= 1) {
      int t = __shfl_up(sc, off);
      if (lane >= off) sc += t;
    }
    if (lane == 63) wsum[wid] = sc;
    __syncthreads();
    if (tid < 64) {
      int ws = (tid < 16) ? wsum[tid] : 0;
#pragma unroll
      for (int off = 1; off < 16; off <<= 1) {
        int t = __shfl_up(ws, off);
        if (tid >= off) ws += t;
      }
      if (tid < 16) wsum[tid] = ws;
    }
    __syncthreads();
    int wbase = (wid > 0) ? wsum[wid - 1] : 0;
    int total = wsum[15];
    int e0 = carry + wbase + (sc - s);
    int4 o;
    o.x = e0; o.y = e0 + v.x; o.z = o.y + v.y; o.w = o.z + v.z;
    if (i0 + 3 < N_NODES) {
      *(int4*)&csr[i0] = o;
      *(int4*)&deg[i0] = o;
    } else if (i0 < N_NODES) {
      csr[i0] = o.x; deg[i0] = o.x;
      if (i0 + 1 < N_NODES) { csr[i0 + 1] = o.y; deg[i0 + 1] = o.y; }
      if (i0 + 2 < N_NODES) { csr[i0 + 2] = o.z; deg[i0 + 2] = o.z; }
    }
    carry += total;
    __syncthreads();
  }
  if (tid == 0) csr[N_NODES] = carry;
}

__global__ __launch_bounds__(256) void scatter_kernel(const int* __restrict__ src,
                                                      const int* __restrict__ dst,
                                                      int* __restrict__ cursor,
                                                      int* __restrict__ ssrc) {
  int e = blockIdx.x * 256 + threadIdx.x;
  int slot = atomicAdd(&cursor[dst[e]], 1);
  ssrc[slot] = src[e];
}

// ---------------- aggregation (bf16 in/out, f32 accum) ----------------

// D=128: wave per node, 1 uint (2 bf16) per lane
__global__ __launch_bounds__(256) void agg1_kernel(const unsigned int* __restrict__ x,
                                                   const int* __restrict__ csr,
                                                   const int* __restrict__ ssrc,
                                                   unsigned int* __restrict__ out) {
  int node = blockIdx.x * 4 + (threadIdx.x >> 6);
  int lane = threadIdx.x & 63;
  unsigned int u = x[(size_t)node * 64 + lane];
  float alo = bf_lo(u), ahi = bf_hi(u);
  int s = csr[node], e = csr[node + 1];
  int i = s;
  for (; i + 4 <= e; i += 4) {
    int n0 = ssrc[i], n1 = ssrc[i + 1], n2 = ssrc[i + 2], n3 = ssrc[i + 3];
    unsigned int v0 = x[(size_t)n0 * 64 + lane];
    unsigned int v1 = x[(size_t)n1 * 64 + lane];
    unsigned int v2 = x[(size_t)n2 * 64 + lane];
    unsigned int v3 = x[(size_t)n3 * 64 + lane];
    alo += bf_lo(v0) + bf_lo(v1) + bf_lo(v2) + bf_lo(v3);
    ahi += bf_hi(v0) + bf_hi(v1) + bf_hi(v2) + bf_hi(v3);
  }
  for (; i < e; i++) {
    unsigned int v = x[(size_t)ssrc[i] * 64 + lane];
    alo += bf_lo(v); ahi += bf_hi(v);
  }
  out[(size_t)node * 64 + lane] = packbf(alo, ahi);
}

// D=256: wave per node, uint2 (4 bf16) per lane
__global__ __launch_bounds__(256) void agg2_kernel(const uint2* __restrict__ x,
                                                   const int* __restrict__ csr,
                                                   const int* __restrict__ ssrc,
                                                   uint2* __restrict__ out) {
  int node = blockIdx.x * 4 + (threadIdx.x >> 6);
  int lane = threadIdx.x & 63;
  uint2 u = x[(size_t)node * 64 + lane];
  float a0 = bf_lo(u.x), a1 = bf_hi(u.x), a2 = bf_lo(u.y), a3 = bf_hi(u.y);
  int s = csr[node], e = csr[node + 1];
  int i = s;
  for (; i + 4 <= e; i += 4) {
    int n0 = ssrc[i], n1 = ssrc[i + 1], n2 = ssrc[i + 2], n3 = ssrc[i + 3];
    uint2 v0 = x[(size_t)n0 * 64 + lane];
    uint2 v1 = x[(size_t)n1 * 64 + lane];
    uint2 v2 = x[(size_t)n2 * 64 + lane];
    uint2 v3 = x[(size_t)n3 * 64 + lane];
    a0 += bf_lo(v0.x) + bf_lo(v1.x) + bf_lo(v2.x) + bf_lo(v3.x);
    a1 += bf_hi(v0.x) + bf_hi(v1.x) + bf_hi(v2.x) + bf_hi(v3.x);
    a2 += bf_lo(v0.y) + bf_lo(v1.y) + bf_lo(v2.y) + bf_lo(v3.y);
    a3 += bf_hi(v0.y) + bf_hi(v1.y) + bf_hi(v2.y) + bf_hi(v3.y);
  }
  for (; i < e; i++) {
    uint2 v = x[(size_t)ssrc[i] * 64 + lane];
    a0 += bf_lo(v.x); a1 += bf_hi(v.x);
    a2 += bf_lo(v.y); a3 += bf_hi(v.y);
  }
  uint2 o;
  o.x = packbf(a0, a1);
  o.y = packbf(a2, a3);
  out[(size_t)node * 64 + lane] = o;
}

// ---------------- bf16 MFMA GEMM: C[N][256] = act(A[N][K] @ W + b) ----------------
// A [N][K] bf16 row-major; Wt [256][K] bf16 (pre-transposed); C [N][256] bf16.
// Block: 512 thr (8 waves, 2x4), tile 128x256, BK=64.
// LDS layout [ko][row][8] -> both staging (linear, global_load_lds) and
// fragment ds_read_b128 are conflict-free (16 lanes read 256B contiguous).
template<int K, bool RELU>
__global__ __launch_bounds__(512, 4)
void gemm_bf16(const unsigned short* __restrict__ A,
               const unsigned short* __restrict__ Wt,
               const float* __restrict__ bias,
               unsigned short* __restrict__ C) {
  __shared__ unsigned short Asl[8 * 128 * 8];  // 16 KB
  __shared__ unsigned short Wsl[8 * 256 * 8];  // 32 KB
  const int tid = threadIdx.x;
  const int lane = tid & 63;
  const int w = tid >> 6;
  const int wm = w >> 2;   // 0..1
  const int wn = w & 3;    // 0..3
  const int rowBase = blockIdx.x * 128;
  const int l15 = lane & 15;
  const int l4 = lane >> 4;  // 0..3

  f32x4 acc[4][4] = {};

  for (int k0 = 0; k0 < K; k0 += 64) {
    // stage A: 1024 chunks of 16B; chunk c -> (ko=c>>7, m=c&127)
#pragma unroll
    for (int i = 0; i < 2; i++) {
      int c = i * 512 + tid;
      int ko = c >> 7, m = c & 127;
      int gr = rowBase + m;
      if (gr >= N_NODES) gr = N_NODES - 1;
      gload16(&A[(size_t)gr * K + k0 + ko * 8], &Asl[(size_t)(i * 512 + w * 64) * 8]);
    }
    // stage Wt: 2048 chunks of 16B; chunk c -> (ko=c>>8, n=c&255)
#pragma unroll
    for (int i = 0; i < 4; i++) {
      int c = i * 512 + tid;
      int ko = c >> 8, n = c & 255;
      gload16(&Wt[(size_t)n * K + k0 + ko * 8], &Wsl[(size_t)(i * 512 + w * 64) * 8]);
    }
    __syncthreads();
#pragma unroll
    for (int kk = 0; kk < 2; kk++) {
      int ko = kk * 4 + l4;
      bf16x8 a[4], b[4];
#pragma unroll
      for (int f = 0; f < 4; f++) {
        a[f] = *(const bf16x8*)&Asl[(size_t)((ko * 128) + wm * 64 + f * 16 + l15) * 8];
        b[f] = *(const bf16x8*)&Wsl[(size_t)((ko * 256) + wn * 64 + f * 16 + l15) * 8];
      }
#pragma unroll
      for (int fm = 0; fm < 4; fm++)
#pragma unroll
        for (int fn = 0; fn < 4; fn++)
          acc[fm][fn] = __builtin_amdgcn_mfma_f32_16x16x32_bf16(a[fm], b[fn], acc[fm][fn], 0, 0, 0);
    }
    __syncthreads();
  }
  // epilogue: D lane mapping col = l&15, row = (l>>4)*4 + reg
#pragma unroll
  for (int fm = 0; fm < 4; fm++) {
    int r0 = rowBase + wm * 64 + fm * 16 + l4 * 4;
#pragma unroll
    for (int fn = 0; fn < 4; fn++) {
      int col = wn * 64 + fn * 16 + l15;
      float bb = bias[col];
#pragma unroll
      for (int j = 0; j < 4; j++) {
        int r = r0 + j;
        if (r < N_NODES) {
          float v = acc[fm][fn][j] + bb;
          if (RELU) v = fmaxf(v, 0.f);
          C[(size_t)r * HID + col] = f2bf(v);
        }
      }
    }
  }
}

// ---------------- pooling (bf16 in, f32 atomics out) ----------------

__global__ __launch_bounds__(256) void pool_kernel(const unsigned short* __restrict__ H,
                                                   const int* __restrict__ batch,
                                                   float* __restrict__ sums,
                                                   float* __restrict__ cnts) {
  int d = threadIdx.x;
  int n0 = blockIdx.x * 128;
  int n1 = n0 + 128; if (n1 > N_NODES) n1 = N_NODES;
  int cur = batch[n0];
  float run = 0.f, runc = 0.f;
  for (int i = n0; i < n1; i++) {
    int b = batch[i];
    if (b != cur) {
      atomicAdd(&sums[(size_t)cur * HID + d], run);
      if (d == 0) atomicAdd(&cnts[cur], runc);
      run = 0.f; runc = 0.f; cur = b;
    }
    run += __uint_as_float(((unsigned int)H[(size_t)i * HID + d]) << 16);
    runc += 1.f;
  }
  atomicAdd(&sums[(size_t)cur * HID + d], run);
  if (d == 0) atomicAdd(&cnts[cur], runc);
}

// ---------------- head: relu(g@wf1+bf1) @ wf2 + bf2 (f32) ----------------

__global__ __launch_bounds__(256) void head_kernel(const float* __restrict__ sums,
                                                   const float* __restrict__ cnts,
                                                   const float* __restrict__ gattr,
                                                   const float* __restrict__ wf1,
                                                   const float* __restrict__ bf1,
                                                   const float* __restrict__ wf2,
                                                   const float* __restrict__ bf2,
                                                   float* __restrict__ out) {
  int g = blockIdx.x, tid = threadIdx.x;
  __shared__ float gv[HID + GA];
  __shared__ float red[256];
  float c = cnts[g]; c = fmaxf(c, 1.0f);
  gv[tid] = sums[(size_t)g * HID + tid] / c;
  if (tid < GA) gv[HID + tid] = gattr[g * GA + tid];
  __syncthreads();
  float acc = bf1[tid];
  for (int k = 0; k < HID + GA; k++)
    acc = fmaf(gv[k], wf1[(size_t)k * HID + tid], acc);
  float h = fmaxf(acc, 0.f);
  red[tid] = h * wf2[tid];
  __syncthreads();
  for (int s = 128; s > 0; s >>= 1) {
    if (tid < s) red[tid] += red[tid + s];
    __syncthreads();
  }
  if (tid == 0) out[g] = red[0] + bf2[0];
}

// ---------------- launch ----------------

extern "C" void kernel_launch(void* const* d_in, const int* in_sizes, int n_in,
                              void* d_out, int out_size, void* d_ws, size_t ws_size,
                              hipStream_t stream) {
  const float* x     = (const float*)d_in[0];
  const int*   eidx  = (const int*)d_in[1];
  const int*   batch = (const int*)d_in[2];
  const float* gattr = (const float*)d_in[3];
  const float* w1a = (const float*)d_in[4];  const float* b1a = (const float*)d_in[5];
  const float* w1b = (const float*)d_in[6];  const float* b1b = (const float*)d_in[7];
  const float* w2a = (const float*)d_in[8];  const float* b2a = (const float*)d_in[9];
  const float* w2b = (const float*)d_in[10]; const float* b2b = (const float*)d_in[11];
  const float* wf1 = (const float*)d_in[12]; const float* bf1 = (const float*)d_in[13];
  const float* wf2 = (const float*)d_in[14]; const float* bf2 = (const float*)d_in[15];
  float* out = (float*)d_out;

  const int* esrc = eidx;
  const int* edst = eidx + N_EDGES;

  char* w = (char*)d_ws;
  auto alloc = [&](size_t bytes) -> void* {
    void* p = (void*)w;
    w += (bytes + 255) & ~(size_t)255;
    return p;
  };
  unsigned short* B0 = (unsigned short*)alloc((size_t)N_NODES * HID * 2);
  unsigned short* B1 = (unsigned short*)alloc((size_t)N_NODES * HID * 2);
  unsigned short* B2 = (unsigned short*)alloc((size_t)N_NODES * HID * 2);
  unsigned short* w1aT = (unsigned short*)alloc(256 * 128 * 2);
  unsigned short* w1bT = (unsigned short*)alloc(256 * 256 * 2);
  unsigned short* w2aT = (unsigned short*)alloc(256 * 256 * 2);
  unsigned short* w2bT = (unsigned short*)alloc(256 * 256 * 2);
  int*   csr    = (int*)alloc((N_NODES + 4) * 4);
  int*   cursor = (int*)alloc((size_t)N_NODES * 4);
  int*   ssrc   = (int*)alloc((size_t)N_EDGES * 4);
  float* sums   = (float*)alloc((size_t)NGRAPH * HID * 4);
  float* cnts   = (float*)alloc(NGRAPH * 4);

  hipMemsetAsync(cursor, 0, (size_t)N_NODES * 4, stream);
  hipMemsetAsync(sums, 0, (size_t)NGRAPH * HID * 4 + 256, stream);  // sums + cnts

  cvt_x_kernel<<<12500, 256, 0, stream>>>(x, B0);
  cvt_w_kernel<<<128, 256, 0, stream>>>(w1a, w1aT, 7);
  cvt_w_kernel<<<256, 256, 0, stream>>>(w1b, w1bT, 8);
  cvt_w_kernel<<<256, 256, 0, stream>>>(w2a, w2aT, 8);
  cvt_w_kernel<<<256, 256, 0, stream>>>(w2b, w2bT, 8);

  hist_kernel<<<N_EDGES / 256, 256, 0, stream>>>(edst, cursor);
  scan_kernel<<<1, 1024, 0, stream>>>(cursor, csr);
  scatter_kernel<<<N_EDGES / 256, 256, 0, stream>>>(esrc, edst, cursor, ssrc);

  // conv1
  agg1_kernel<<<N_NODES / 4, 256, 0, stream>>>((const unsigned int*)B0, csr, ssrc,
                                               (unsigned int*)B1);
  gemm_bf16<128, true><<<(N_NODES + 127) / 128, 512, 0, stream>>>(B1, w1aT, b1a, B2);
  gemm_bf16<256, true><<<(N_NODES + 127) / 128, 512, 0, stream>>>(B2, w1bT, b1b, B0);
  // conv2
  agg2_kernel<<<N_NODES / 4, 256, 0, stream>>>((const uint2*)B0, csr, ssrc, (uint2*)B1);
  gemm_bf16<256, true><<<(N_NODES + 127) / 128, 512, 0, stream>>>(B1, w2aT, b2a, B2);
  gemm_bf16<256, false><<<(N_NODES + 127) / 128, 512, 0, stream>>>(B2, w2bT, b2b, B0);
  // pool + head
  pool_kernel<<<(N_NODES + 127) / 128, 256, 0, stream>>>(B0, batch, sums, cnts);
  head_kernel<<<NGRAPH, 256, 0, stream>>>(sums, cnts, gattr, wf1, bf1, wf2, bf2, out);
}

// Round 3
// 503.483 us; speedup vs baseline: 2.9271x; 1.3347x over previous
//
#include <hip/hip_runtime.h>

#define N_NODES 100000
#define N_EDGES 1600000
#define NGRAPH  64
#define DIN     128
#define HID     256
#define GA      6

// bucketed CSR build
#define NBUCK  98        // ceil(100000 / 1024)
#define BSHIFT 10        // 1024 nodes per bucket
#define BCAP   20480     // per-bucket capacity (mean 16384, +32 sigma)

typedef __attribute__((ext_vector_type(8))) short bf16x8;
typedef __attribute__((ext_vector_type(4))) float f32x4;

__device__ __forceinline__ unsigned short f2bf(float f) {
  unsigned int u = __float_as_uint(f);
  u += 0x7fffu + ((u >> 16) & 1u);
  return (unsigned short)(u >> 16);
}
__device__ __forceinline__ float bf_lo(unsigned int u) { return __uint_as_float(u << 16); }
__device__ __forceinline__ float bf_hi(unsigned int u) { return __uint_as_float(u & 0xffff0000u); }
__device__ __forceinline__ unsigned int packbf(float lo, float hi) {
  return (unsigned int)f2bf(lo) | ((unsigned int)f2bf(hi) << 16);
}

__device__ __forceinline__ void gload16(const void* g, void* l) {
  __builtin_amdgcn_global_load_lds(
      (const __attribute__((address_space(1))) unsigned int*)g,
      (__attribute__((address_space(3))) unsigned int*)l, 16, 0, 0);
}

// ---------------- prep: f32 -> bf16 conversions ----------------

__global__ __launch_bounds__(256) void cvt_x_kernel(const float* __restrict__ in,
                                                    unsigned short* __restrict__ out) {
  size_t idx = ((size_t)blockIdx.x * 256 + threadIdx.x) * 4;  // 12.8M total, exact
  float4 v = *(const float4*)&in[idx];
  ushort4 o;
  o.x = f2bf(v.x); o.y = f2bf(v.y); o.z = f2bf(v.z); o.w = f2bf(v.w);
  *(ushort4*)&out[idx] = o;
}

// all four weight transposes in one launch: out[n*K+k] = bf16(in[k*256+n])
__global__ __launch_bounds__(256) void cvt_w_all(const float* __restrict__ w1a,
                                                 const float* __restrict__ w1b,
                                                 const float* __restrict__ w2a,
                                                 const float* __restrict__ w2b,
                                                 unsigned short* __restrict__ o1a,
                                                 unsigned short* __restrict__ o1b,
                                                 unsigned short* __restrict__ o2a,
                                                 unsigned short* __restrict__ o2b) {
  int bid = blockIdx.x, tid = threadIdx.x;
  const float* in; unsigned short* out; int shift, idx;
  if (bid < 128)      { in = w1a; out = o1a; shift = 7; idx = bid * 256 + tid; }
  else if (bid < 384) { in = w1b; out = o1b; shift = 8; idx = (bid - 128) * 256 + tid; }
  else if (bid < 640) { in = w2a; out = o2a; shift = 8; idx = (bid - 384) * 256 + tid; }
  else                { in = w2b; out = o2b; shift = 8; idx = (bid - 640) * 256 + tid; }
  int K = 1 << shift;
  int n = idx >> shift;
  int k = idx & (K - 1);
  out[idx] = f2bf(in[(size_t)k * HID + n]);
}

// ---------------- pass 1: bin edges by dst>>10 with block-local sort ----------------
// tmp region per bucket b: [b*BCAP, b*BCAP+cnt[b]); packed = src | (dst&1023)<<17

__global__ __launch_bounds__(256) void bin_kernel(const int* __restrict__ esrc,
                                                  const int* __restrict__ edst,
                                                  int* __restrict__ cursor,
                                                  unsigned int* __restrict__ tmp) {
  __shared__ unsigned int pk[4096];
  __shared__ int hist[NBUCK], lbase[NBUCK + 1], gbase[NBUCK], lcur[NBUCK];
  const int tid = threadIdx.x;
  const int lane = tid & 63;
  const int ebase = blockIdx.x * 4096;
  const int n = min(4096, N_EDGES - ebase);
  if (tid < NBUCK) hist[tid] = 0;
  __syncthreads();
  unsigned int pkv[16]; int bk[16];
#pragma unroll
  for (int i = 0; i < 16; i++) {
    int e = ebase + i * 256 + tid;
    bk[i] = -1;
    if (e < N_EDGES) {
      int s = esrc[e], d = edst[e];
      bk[i] = d >> BSHIFT;
      pkv[i] = (unsigned int)s | ((unsigned int)(d & ((1 << BSHIFT) - 1)) << 17);
      atomicAdd(&hist[bk[i]], 1);
    }
  }
  __syncthreads();
  if (tid < 64) {               // wave-0 exclusive scan of 98 counts (2/lane)
    int i0 = 2 * tid, i1 = i0 + 1;
    int a0 = (i0 < NBUCK) ? hist[i0] : 0;
    int a1 = (i1 < NBUCK) ? hist[i1] : 0;
    int p = a0 + a1, sc = p;
#pragma unroll
    for (int off = 1; off < 64; off <<= 1) {
      int t = __shfl_up(sc, off);
      if (lane >= off) sc += t;
    }
    int excl = sc - p;
    if (i0 < NBUCK) lbase[i0] = excl;
    if (i1 < NBUCK) lbase[i1] = excl + a0;
    if (tid == 63) lbase[NBUCK] = sc;   // total
  }
  __syncthreads();
  if (tid < NBUCK) {
    int c = hist[tid];
    gbase[tid] = c ? atomicAdd(&cursor[tid], c) : 0;
    lcur[tid] = lbase[tid];
  }
  __syncthreads();
#pragma unroll
  for (int i = 0; i < 16; i++) {
    if (bk[i] >= 0) {
      int pos = atomicAdd(&lcur[bk[i]], 1);
      pk[pos] = pkv[i];
    }
  }
  __syncthreads();
#pragma unroll
  for (int i = 0; i < 16; i++) {
    int idx = i * 256 + tid;
    if (idx < n) {
      int lo = 0, hi = NBUCK;           // find bucket: lbase[lo] <= idx < lbase[lo+1]
      while (hi - lo > 1) {
        int mid = (lo + hi) >> 1;
        if (lbase[mid] <= idx) lo = mid; else hi = mid;
      }
      tmp[(size_t)lo * BCAP + gbase[lo] + (idx - lbase[lo])] = pk[idx];
    }
  }
}

// ---------------- pass 2: per-bucket counting sort -> csr + ssrc ----------------

__global__ __launch_bounds__(512) void sort_kernel(const unsigned int* __restrict__ tmp,
                                                   const int* __restrict__ cnt,
                                                   int* __restrict__ csr,
                                                   int* __restrict__ ssrc) {
  __shared__ int nhist[1024], ncur[1024];
  __shared__ int bb[NBUCK];
  __shared__ int wsum[8];
  const int b = blockIdx.x;
  const int tid = threadIdx.x;
  const int lane = tid & 63, wid = tid >> 6;
  if (tid < 64) {               // scan bucket counts -> edge bases
    int i0 = 2 * tid, i1 = i0 + 1;
    int a0 = (i0 < NBUCK) ? cnt[i0] : 0;
    int a1 = (i1 < NBUCK) ? cnt[i1] : 0;
    int p = a0 + a1, sc = p;
#pragma unroll
    for (int off = 1; off < 64; off <<= 1) {
      int t = __shfl_up(sc, off);
      if (lane >= off) sc += t;
    }
    int excl = sc - p;
    if (i0 < NBUCK) bb[i0] = excl;
    if (i1 < NBUCK) bb[i1] = excl + a0;
  }
  nhist[tid] = 0; nhist[tid + 512] = 0;
  __syncthreads();
  const int myCnt = cnt[b];
  const int ebase = bb[b];
  const unsigned int* srcp = tmp + (size_t)b * BCAP;
  for (int i = tid; i < myCnt; i += 512)
    atomicAdd(&nhist[srcp[i] >> 17], 1);
  __syncthreads();
  // block scan of 1024 node counts (2/thread, 8 waves)
  int i0 = 2 * tid;
  int a0 = nhist[i0], a1 = nhist[i0 + 1];
  int p = a0 + a1, sc = p;
#pragma unroll
  for (int off = 1; off < 64; off <<= 1) {
    int t = __shfl_up(sc, off);
    if (lane >= off) sc += t;
  }
  if (lane == 63) wsum[wid] = sc;
  __syncthreads();
  if (tid < 8) {
    int ws = wsum[tid];
#pragma unroll
    for (int off = 1; off < 8; off <<= 1) {
      int t = __shfl_up(ws, off);
      if (tid >= off) ws += t;
    }
    wsum[tid] = ws;
  }
  __syncthreads();
  int excl = ((wid > 0) ? wsum[wid - 1] : 0) + sc - p;
  ncur[i0] = excl;
  ncur[i0 + 1] = excl + a0;
  int node0 = (b << BSHIFT) + i0;
  if (node0 < N_NODES) csr[node0] = ebase + excl;
  if (node0 + 1 < N_NODES) csr[node0 + 1] = ebase + excl + a0;
  if (b == 0 && tid == 0) csr[N_NODES] = N_EDGES;
  __syncthreads();
  for (int i = tid; i < myCnt; i += 512) {
    unsigned int pe = srcp[i];
    int pos = atomicAdd(&ncur[pe >> 17], 1);     // bucket-relative slot
    ssrc[ebase + pos] = (int)(pe & 0x1FFFF);     // single-block 65KB region: full lines
  }
}

// ---------------- aggregation (bf16 in/out, f32 accum) ----------------

__global__ __launch_bounds__(256) void agg1_kernel(const unsigned int* __restrict__ x,
                                                   const int* __restrict__ csr,
                                                   const int* __restrict__ ssrc,
                                                   unsigned int* __restrict__ out) {
  int node = blockIdx.x * 4 + (threadIdx.x >> 6);
  int lane = threadIdx.x & 63;
  unsigned int u = x[(size_t)node * 64 + lane];
  float alo = bf_lo(u), ahi = bf_hi(u);
  int s = csr[node], e = csr[node + 1];
  int i = s;
  for (; i + 4 <= e; i += 4) {
    int n0 = ssrc[i], n1 = ssrc[i + 1], n2 = ssrc[i + 2], n3 = ssrc[i + 3];
    unsigned int v0 = x[(size_t)n0 * 64 + lane];
    unsigned int v1 = x[(size_t)n1 * 64 + lane];
    unsigned int v2 = x[(size_t)n2 * 64 + lane];
    unsigned int v3 = x[(size_t)n3 * 64 + lane];
    alo += bf_lo(v0) + bf_lo(v1) + bf_lo(v2) + bf_lo(v3);
    ahi += bf_hi(v0) + bf_hi(v1) + bf_hi(v2) + bf_hi(v3);
  }
  for (; i < e; i++) {
    unsigned int v = x[(size_t)ssrc[i] * 64 + lane];
    alo += bf_lo(v); ahi += bf_hi(v);
  }
  out[(size_t)node * 64 + lane] = packbf(alo, ahi);
}

__global__ __launch_bounds__(256) void agg2_kernel(const uint2* __restrict__ x,
                                                   const int* __restrict__ csr,
                                                   const int* __restrict__ ssrc,
                                                   uint2* __restrict__ out) {
  int node = blockIdx.x * 4 + (threadIdx.x >> 6);
  int lane = threadIdx.x & 63;
  uint2 u = x[(size_t)node * 64 + lane];
  float a0 = bf_lo(u.x), a1 = bf_hi(u.x), a2 = bf_lo(u.y), a3 = bf_hi(u.y);
  int s = csr[node], e = csr[node + 1];
  int i = s;
  for (; i + 4 <= e; i += 4) {
    int n0 = ssrc[i], n1 = ssrc[i + 1], n2 = ssrc[i + 2], n3 = ssrc[i + 3];
    uint2 v0 = x[(size_t)n0 * 64 + lane];
    uint2 v1 = x[(size_t)n1 * 64 + lane];
    uint2 v2 = x[(size_t)n2 * 64 + lane];
    uint2 v3 = x[(size_t)n3 * 64 + lane];
    a0 += bf_lo(v0.x) + bf_lo(v1.x) + bf_lo(v2.x) + bf_lo(v3.x);
    a1 += bf_hi(v0.x) + bf_hi(v1.x) + bf_hi(v2.x) + bf_hi(v3.x);
    a2 += bf_lo(v0.y) + bf_lo(v1.y) + bf_lo(v2.y) + bf_lo(v3.y);
    a3 += bf_hi(v0.y) + bf_hi(v1.y) + bf_hi(v2.y) + bf_hi(v3.y);
  }
  for (; i < e; i++) {
    uint2 v = x[(size_t)ssrc[i] * 64 + lane];
    a0 += bf_lo(v.x); a1 += bf_hi(v.x);
    a2 += bf_lo(v.y); a3 += bf_hi(v.y);
  }
  uint2 o;
  o.x = packbf(a0, a1);
  o.y = packbf(a2, a3);
  out[(size_t)node * 64 + lane] = o;
}

// ---------------- bf16 MFMA GEMM (tile 128x256, BK=64, 8 waves) ----------------

template<int K, bool RELU>
__global__ __launch_bounds__(512, 4)
void gemm_bf16(const unsigned short* __restrict__ A,
               const unsigned short* __restrict__ Wt,
               const float* __restrict__ bias,
               unsigned short* __restrict__ C) {
  __shared__ unsigned short Asl[8 * 128 * 8];  // 16 KB
  __shared__ unsigned short Wsl[8 * 256 * 8];  // 32 KB
  const int tid = threadIdx.x;
  const int lane = tid & 63;
  const int w = tid >> 6;
  const int wm = w >> 2;
  const int wn = w & 3;
  const int rowBase = blockIdx.x * 128;
  const int l15 = lane & 15;
  const int l4 = lane >> 4;

  f32x4 acc[4][4] = {};

  for (int k0 = 0; k0 < K; k0 += 64) {
#pragma unroll
    for (int i = 0; i < 2; i++) {
      int c = i * 512 + tid;
      int ko = c >> 7, m = c & 127;
      int gr = rowBase + m;
      if (gr >= N_NODES) gr = N_NODES - 1;
      gload16(&A[(size_t)gr * K + k0 + ko * 8], &Asl[(size_t)(i * 512 + w * 64) * 8]);
    }
#pragma unroll
    for (int i = 0; i < 4; i++) {
      int c = i * 512 + tid;
      int ko = c >> 8, n = c & 255;
      gload16(&Wt[(size_t)n * K + k0 + ko * 8], &Wsl[(size_t)(i * 512 + w * 64) * 8]);
    }
    __syncthreads();
#pragma unroll
    for (int kk = 0; kk < 2; kk++) {
      int ko = kk * 4 + l4;
      bf16x8 a[4], b[4];
#pragma unroll
      for (int f = 0; f < 4; f++) {
        a[f] = *(const bf16x8*)&Asl[(size_t)((ko * 128) + wm * 64 + f * 16 + l15) * 8];
        b[f] = *(const bf16x8*)&Wsl[(size_t)((ko * 256) + wn * 64 + f * 16 + l15) * 8];
      }
#pragma unroll
      for (int fm = 0; fm < 4; fm++)
#pragma unroll
        for (int fn = 0; fn < 4; fn++)
          acc[fm][fn] = __builtin_amdgcn_mfma_f32_16x16x32_bf16(a[fm], b[fn], acc[fm][fn], 0, 0, 0);
    }
    __syncthreads();
  }
#pragma unroll
  for (int fm = 0; fm < 4; fm++) {
    int r0 = rowBase + wm * 64 + fm * 16 + l4 * 4;
#pragma unroll
    for (int fn = 0; fn < 4; fn++) {
      int col = wn * 64 + fn * 16 + l15;
      float bb = bias[col];
#pragma unroll
      for (int j = 0; j < 4; j++) {
        int r = r0 + j;
        if (r < N_NODES) {
          float v = acc[fm][fn][j] + bb;
          if (RELU) v = fmaxf(v, 0.f);
          C[(size_t)r * HID + col] = f2bf(v);
        }
      }
    }
  }
}

// ---------------- pooling ----------------

__global__ __launch_bounds__(256) void pool_kernel(const unsigned short* __restrict__ H,
                                                   const int* __restrict__ batch,
                                                   float* __restrict__ sums,
                                                   float* __restrict__ cnts) {
  int d = threadIdx.x;
  int n0 = blockIdx.x * 128;
  int n1 = n0 + 128; if (n1 > N_NODES) n1 = N_NODES;
  int cur = batch[n0];
  float run = 0.f, runc = 0.f;
  for (int i = n0; i < n1; i++) {
    int b = batch[i];
    if (b != cur) {
      atomicAdd(&sums[(size_t)cur * HID + d], run);
      if (d == 0) atomicAdd(&cnts[cur], runc);
      run = 0.f; runc = 0.f; cur = b;
    }
    run += __uint_as_float(((unsigned int)H[(size_t)i * HID + d]) << 16);
    runc += 1.f;
  }
  atomicAdd(&sums[(size_t)cur * HID + d], run);
  if (d == 0) atomicAdd(&cnts[cur], runc);
}

// ---------------- head ----------------

__global__ __launch_bounds__(256) void head_kernel(const float* __restrict__ sums,
                                                   const float* __restrict__ cnts,
                                                   const float* __restrict__ gattr,
                                                   const float* __restrict__ wf1,
                                                   const float* __restrict__ bf1,
                                                   const float* __restrict__ wf2,
                                                   const float* __restrict__ bf2,
                                                   float* __restrict__ out) {
  int g = blockIdx.x, tid = threadIdx.x;
  __shared__ float gv[HID + GA];
  __shared__ float red[256];
  float c = cnts[g]; c = fmaxf(c, 1.0f);
  gv[tid] = sums[(size_t)g * HID + tid] / c;
  if (tid < GA) gv[HID + tid] = gattr[g * GA + tid];
  __syncthreads();
  float acc = bf1[tid];
  for (int k = 0; k < HID + GA; k++)
    acc = fmaf(gv[k], wf1[(size_t)k * HID + tid], acc);
  float h = fmaxf(acc, 0.f);
  red[tid] = h * wf2[tid];
  __syncthreads();
  for (int s = 128; s > 0; s >>= 1) {
    if (tid < s) red[tid] += red[tid + s];
    __syncthreads();
  }
  if (tid == 0) out[g] = red[0] + bf2[0];
}

// ---------------- launch ----------------

extern "C" void kernel_launch(void* const* d_in, const int* in_sizes, int n_in,
                              void* d_out, int out_size, void* d_ws, size_t ws_size,
                              hipStream_t stream) {
  const float* x     = (const float*)d_in[0];
  const int*   eidx  = (const int*)d_in[1];
  const int*   batch = (const int*)d_in[2];
  const float* gattr = (const float*)d_in[3];
  const float* w1a = (const float*)d_in[4];  const float* b1a = (const float*)d_in[5];
  const float* w1b = (const float*)d_in[6];  const float* b1b = (const float*)d_in[7];
  const float* w2a = (const float*)d_in[8];  const float* b2a = (const float*)d_in[9];
  const float* w2b = (const float*)d_in[10]; const float* b2b = (const float*)d_in[11];
  const float* wf1 = (const float*)d_in[12]; const float* bf1 = (const float*)d_in[13];
  const float* wf2 = (const float*)d_in[14]; const float* bf2 = (const float*)d_in[15];
  float* out = (float*)d_out;

  const int* esrc = eidx;
  const int* edst = eidx + N_EDGES;

  char* w = (char*)d_ws;
  auto alloc = [&](size_t bytes) -> void* {
    void* p = (void*)w;
    w += (bytes + 255) & ~(size_t)255;
    return p;
  };
  unsigned short* B0 = (unsigned short*)alloc((size_t)N_NODES * HID * 2);
  unsigned short* B1 = (unsigned short*)alloc((size_t)N_NODES * HID * 2);
  unsigned short* B2 = (unsigned short*)alloc((size_t)N_NODES * HID * 2);
  unsigned short* w1aT = (unsigned short*)alloc(256 * 128 * 2);
  unsigned short* w1bT = (unsigned short*)alloc(256 * 256 * 2);
  unsigned short* w2aT = (unsigned short*)alloc(256 * 256 * 2);
  unsigned short* w2bT = (unsigned short*)alloc(256 * 256 * 2);
  int*   csr    = (int*)alloc((N_NODES + 4) * 4);
  int*   cursor = (int*)alloc(NBUCK * 4);
  unsigned int* tmp = (unsigned int*)alloc((size_t)NBUCK * BCAP * 4);
  int*   ssrc   = (int*)alloc((size_t)N_EDGES * 4);
  float* sums   = (float*)alloc((size_t)NGRAPH * HID * 4);
  float* cnts   = (float*)alloc(NGRAPH * 4);

  hipMemsetAsync(cursor, 0, NBUCK * 4, stream);
  hipMemsetAsync(sums, 0, (size_t)NGRAPH * HID * 4 + 256, stream);  // sums + cnts

  cvt_x_kernel<<<12500, 256, 0, stream>>>(x, B0);
  cvt_w_all<<<896, 256, 0, stream>>>(w1a, w1b, w2a, w2b, w1aT, w1bT, w2aT, w2bT);

  bin_kernel<<<(N_EDGES + 4095) / 4096, 256, 0, stream>>>(esrc, edst, cursor, tmp);
  sort_kernel<<<NBUCK, 512, 0, stream>>>(tmp, cursor, csr, ssrc);

  // conv1
  agg1_kernel<<<N_NODES / 4, 256, 0, stream>>>((const unsigned int*)B0, csr, ssrc,
                                               (unsigned int*)B1);
  gemm_bf16<128, true><<<(N_NODES + 127) / 128, 512, 0, stream>>>(B1, w1aT, b1a, B2);
  gemm_bf16<256, true><<<(N_NODES + 127) / 128, 512, 0, stream>>>(B2, w1bT, b1b, B0);
  // conv2
  agg2_kernel<<<N_NODES / 4, 256, 0, stream>>>((const uint2*)B0, csr, ssrc, (uint2*)B1);
  gemm_bf16<256, true><<<(N_NODES + 127) / 128, 512, 0, stream>>>(B1, w2aT, b2a, B2);
  gemm_bf16<256, false><<<(N_NODES + 127) / 128, 512, 0, stream>>>(B2, w2bT, b2b, B0);
  // pool + head
  pool_kernel<<<(N_NODES + 127) / 128, 256, 0, stream>>>(B0, batch, sums, cnts);
  head_kernel<<<NGRAPH, 256, 0, stream>>>(sums, cnts, gattr, wf1, bf1, wf2, bf2, out);
}